// Round 1
// baseline (1337.483 us; speedup 1.0000x reference)
//
#include <hip/hip_runtime.h>

// LSTM: T=1024, B=2048, INPUT=2, H=64. Strategy: batch-parallel, fully fused.
// One block (256 threads) owns 2 batch elements for the entire T loop.
// Thread t owns gate-row t with its 64 W_hh weights in registers; h is
// broadcast from LDS. Gate type == wave index -> uniform activation branch.

constexpr int T_STEPS = 1024;
constexpr int BATCH   = 2048;
constexpr int H       = 64;
constexpr int G       = 4 * H;   // 256 gate rows

__device__ __forceinline__ float fast_sigmoid(float v) {
    return 1.0f / (1.0f + __expf(-v));
}
__device__ __forceinline__ float fast_tanh(float v) {
    // tanh(v) = 2*sigmoid(2v) - 1 ; saturates correctly for |v| large
    return 2.0f / (1.0f + __expf(-2.0f * v)) - 1.0f;
}

__global__ __launch_bounds__(256, 4) void lstm_fused(
    const float* __restrict__ x,      // (T, B, 2)
    const float* __restrict__ W_ih,   // (256, 2)
    const float* __restrict__ W_hh,   // (256, 64)
    const float* __restrict__ b_ih,   // (256)
    const float* __restrict__ b_hh,   // (256)
    const float* __restrict__ W_fc,   // (1, 64)
    const float* __restrict__ b_fc,   // (1)
    float* __restrict__ out)          // (B, 1)
{
    const int t  = threadIdx.x;       // gate row 0..255
    const int b0 = blockIdx.x * 2;    // two batch elements per block

    __shared__ __align__(16) float sh[2][H];    // hidden state per batch elem
    __shared__ __align__(16) float sact[2][G];  // activated gates per batch elem

    // --- per-thread constants ---------------------------------------------
    float4 w4[16];
    const float4* wrow = reinterpret_cast<const float4*>(W_hh + t * H);
    #pragma unroll
    for (int k = 0; k < 16; ++k) w4[k] = wrow[k];

    const float wx0  = W_ih[t * 2 + 0];
    const float wx1  = W_ih[t * 2 + 1];
    const float bias = b_ih[t] + b_hh[t];
    const int   gate = t >> 6;        // 0:i 1:f 2:g 3:o (wave-uniform)

    float c0 = 0.0f, c1 = 0.0f;
    if (t < H) { sh[0][t] = 0.0f; sh[1][t] = 0.0f; }
    __syncthreads();

    // x for (step, b0..b0+1) is 4 contiguous floats, 16B-aligned.
    const float4* xp = reinterpret_cast<const float4*>(x + b0 * 2);
    constexpr int XSTRIDE4 = BATCH * 2 / 4;     // float4 stride per timestep
    float4 xv = xp[0];

    for (int step = 0; step < T_STEPS; ++step) {
        float4 xn = xv;
        if (step + 1 < T_STEPS) xn = xp[(step + 1) * XSTRIDE4];

        float acc0 = fmaf(wx0, xv.x, fmaf(wx1, xv.y, bias));
        float acc1 = fmaf(wx0, xv.z, fmaf(wx1, xv.w, bias));

        const float4* h40 = reinterpret_cast<const float4*>(sh[0]);
        const float4* h41 = reinterpret_cast<const float4*>(sh[1]);
        #pragma unroll
        for (int k = 0; k < 16; ++k) {
            const float4 hv0 = h40[k];
            const float4 hv1 = h41[k];
            acc0 = fmaf(w4[k].x, hv0.x, acc0);
            acc1 = fmaf(w4[k].x, hv1.x, acc1);
            acc0 = fmaf(w4[k].y, hv0.y, acc0);
            acc1 = fmaf(w4[k].y, hv1.y, acc1);
            acc0 = fmaf(w4[k].z, hv0.z, acc0);
            acc1 = fmaf(w4[k].z, hv1.z, acc1);
            acc0 = fmaf(w4[k].w, hv0.w, acc0);
            acc1 = fmaf(w4[k].w, hv1.w, acc1);
        }

        float a0, a1;
        if (gate == 2) { a0 = fast_tanh(acc0);    a1 = fast_tanh(acc1); }
        else           { a0 = fast_sigmoid(acc0); a1 = fast_sigmoid(acc1); }
        sact[0][t] = a0;
        sact[1][t] = a1;
        __syncthreads();

        if (t < H) {
            const float i0 = sact[0][t];
            const float f0 = sact[0][H + t];
            const float g0 = sact[0][2 * H + t];
            const float o0 = sact[0][3 * H + t];
            c0 = fmaf(f0, c0, i0 * g0);
            sh[0][t] = o0 * fast_tanh(c0);

            const float i1 = sact[1][t];
            const float f1 = sact[1][H + t];
            const float g1 = sact[1][2 * H + t];
            const float o1 = sact[1][3 * H + t];
            c1 = fmaf(f1, c1, i1 * g1);
            sh[1][t] = o1 * fast_tanh(c1);
        }
        __syncthreads();

        xv = xn;
    }

    // --- fused fc epilogue: out[b] = h . W_fc + b_fc ----------------------
    if (t < H) {  // wave 0 exactly
        float v0 = sh[0][t] * W_fc[t];
        float v1 = sh[1][t] * W_fc[t];
        #pragma unroll
        for (int off = 32; off; off >>= 1) {
            v0 += __shfl_down(v0, off);
            v1 += __shfl_down(v1, off);
        }
        if (t == 0) {
            const float bf = b_fc[0];
            out[b0 + 0] = v0 + bf;
            out[b0 + 1] = v1 + bf;
        }
    }
}

extern "C" void kernel_launch(void* const* d_in, const int* in_sizes, int n_in,
                              void* d_out, int out_size, void* d_ws, size_t ws_size,
                              hipStream_t stream) {
    const float* x    = (const float*)d_in[0];
    const float* W_ih = (const float*)d_in[1];
    const float* W_hh = (const float*)d_in[2];
    const float* b_ih = (const float*)d_in[3];
    const float* b_hh = (const float*)d_in[4];
    const float* W_fc = (const float*)d_in[5];
    const float* b_fc = (const float*)d_in[6];
    float* out = (float*)d_out;

    dim3 grid(BATCH / 2);   // 1024 blocks, 2 batch elements each
    dim3 block(256);
    lstm_fused<<<grid, block, 0, stream>>>(x, W_ih, W_hh, b_ih, b_hh, W_fc, b_fc, out);
}